// Round 2
// baseline (2102.820 us; speedup 1.0000x reference)
//
#include <hip/hip_runtime.h>

typedef unsigned short ushort;
typedef unsigned int uint;
typedef __bf16 bf16_t;
typedef bf16_t bf16x8 __attribute__((ext_vector_type(8)));
typedef float f32x4 __attribute__((ext_vector_type(4)));

#define B_ 2048
#define T_ 512
#define D_ 5
#define H_ 128
#define C_ 10
#define BT 16      // batch tile per workgroup
#define BLK 512    // 8 waves
#define H0STR 168  // h0s row stride in ushorts (160 used + 8 pad)
#define H1STR 136  // h1s row stride (128 used + 8 pad)

static __device__ __forceinline__ float b2f(ushort u) {
    return __builtin_bit_cast(float, ((uint)u) << 16);
}
static __device__ __forceinline__ ushort f2b(float f) {
    uint u = __builtin_bit_cast(uint, f);
    u += 0x7FFFu + ((u >> 16) & 1u);   // RNE
    return (ushort)(u >> 16);
}
static __device__ __forceinline__ float sigf(float x) {
    x = fminf(fmaxf(x, -30.f), 30.f);                 // NaN/Inf guard
    return __builtin_amdgcn_rcpf(1.0f + __expf(-x));
}
static __device__ __forceinline__ float tanhf_(float x) {
    x = fminf(fmaxf(x, -15.f), 15.f);                 // NaN/Inf guard
    return 1.0f - 2.0f * __builtin_amdgcn_rcpf(1.0f + __expf(2.0f * x));
}
// dual-dtype scalar load: m32 ? float32 : bf16
static __device__ __forceinline__ float ldf(const void* p, long i, bool m32) {
    return m32 ? ((const float*)p)[i] : b2f(((const ushort*)p)[i]);
}
static __device__ __forceinline__ bf16x8 ld16(const ushort* p) {
    return __builtin_bit_cast(bf16x8, *(const uint4*)p);
}
// dual-dtype 8-element fragment load (init-time only)
static __device__ __forceinline__ bf16x8 ldfrag(const void* p, long idx, bool m32) {
    if (!m32) return ld16((const ushort*)p + idx);
    const float* f = (const float*)p + idx;
    union { ushort u[8]; bf16x8 v; } r;
#pragma unroll
    for (int j = 0; j < 8; ++j) r.u[j] = f2b(f[j]);
    return r.v;
}
static __device__ __forceinline__ f32x4 splat4(float v) {
    f32x4 r = {v, v, v, v};
    return r;
}

// ---- dtype detector: true-bf16 weights all have |w|<0.1 -> zero large-exponent
// patterns; f32-stored weights read as ushorts expose ~8k random mantissa halves,
// ~half of which decode as |bf16| >= 16. Writes flag every launch (graph-safe).
__global__ void detect_dtype(const ushort* __restrict__ w, int* __restrict__ flag) {
    __shared__ int cnt;
    if (threadIdx.x == 0) cnt = 0;
    __syncthreads();
    int local = 0;
    for (int i = threadIdx.x; i < 16384; i += 256)
        if ((uint)(w[i] & 0x7F80u) >= 0x4180u) ++local;   // |v| >= 16
    atomicAdd(&cnt, local);
    __syncthreads();
    if (threadIdx.x == 0) *flag = (cnt > 512) ? 1 : 0;
}

__global__ __launch_bounds__(BLK) void lstm2_fused(
    const void* __restrict__ x,
    const void* __restrict__ wih0, const void* __restrict__ whh0,
    const void* __restrict__ bih0, const void* __restrict__ bhh0,
    const void* __restrict__ wih1, const void* __restrict__ whh1,
    const void* __restrict__ bih1, const void* __restrict__ bhh1,
    const void* __restrict__ cw1, const void* __restrict__ cb1,
    const void* __restrict__ cw2, const void* __restrict__ cb2,
    const int* __restrict__ flag, void* __restrict__ out)
{
    __shared__ __align__(16) ushort h0s[BT * H0STR]; // [16][0..127]=h0, [128..132]=x_t, [133]=1.0, rest 0
    __shared__ __align__(16) ushort h1s[BT * H1STR]; // [16][0..127]=h1(t-1) bf16
    __shared__ float h1fs[BT * H_];                  // final h1 in f32
    __shared__ float rs[BT * 64];                    // classifier hidden

    const bool m32 = (*flag) != 0;   // uniform
    const int tid  = threadIdx.x;
    const int w    = tid >> 6;
    const int lane = tid & 63;
    const int quad = lane >> 4;
    const int l16  = lane & 15;
    const int bt0  = blockIdx.x * BT;

    // ---- pre-stage x(t=0) + constant cols into h0s[., 128..159]
    {
        int row = tid >> 5, cc = tid & 31; // 16 rows x 32 cols = 512 threads
        ushort v = 0;
        if (cc < 5)       v = f2b(ldf(x, ((long)(bt0 + row) * T_ + 0) * D_ + cc, m32));
        else if (cc == 5) v = 0x3F80; // bf16(1.0) -> bias column
        h0s[row * H0STR + 128 + cc] = v;
    }

    // ---- persistent register-resident weight fragments
    // B-frag (16x16x32): lane holds W[n = tile + l16][k = kt*32 + quad*8 + j], j=0..7
    bf16x8 wh0c[4][5]; // layer0: kt 0..3 = w_hh0, kt 4 = [w_ih0 | bias | 0]
    bf16x8 wi1f[4][4]; // layer1, h0 part
    bf16x8 wh1f[4][4]; // layer1, h1 part
    float  b1v[4];
#pragma unroll
    for (int g = 0; g < 4; ++g) {
        const int n = g * 128 + w * 16 + l16; // row in 4H=512 gate dim
#pragma unroll
        for (int kt = 0; kt < 4; ++kt) {
            wh0c[g][kt] = ldfrag(whh0, (long)n * 128 + kt * 32 + quad * 8, m32);
            wi1f[g][kt] = ldfrag(wih1, (long)n * 128 + kt * 32 + quad * 8, m32);
            wh1f[g][kt] = ldfrag(whh1, (long)n * 128 + kt * 32 + quad * 8, m32);
        }
        union { ushort u[8]; bf16x8 v; } xt;
#pragma unroll
        for (int j = 0; j < 8; ++j) xt.u[j] = 0;
        if (quad == 0) { // only k=128..135 is live in the x-tile
#pragma unroll
            for (int j = 0; j < 5; ++j) xt.u[j] = f2b(ldf(wih0, (long)n * D_ + j, m32));
            xt.u[5] = f2b(ldf(bih0, n, m32) + ldf(bhh0, n, m32)); // bias via 1.0 column
        }
        wh0c[g][4] = xt.v;
        b1v[g] = ldf(bih1, n, m32) + ldf(bhh1, n, m32);
    }

    __syncthreads();

    // ---- recurrent state
    bf16x8 h0f[5];
    {
        uint4 z = make_uint4(0, 0, 0, 0);
        h0f[0] = h0f[1] = h0f[2] = h0f[3] = __builtin_bit_cast(bf16x8, z); // h0(-1)=0
    }
    h0f[4] = ld16(&h0s[l16 * H0STR + 128 + quad * 8]); // x(0) + bias col

    f32x4 c0 = splat4(0.f), c1 = splat4(0.f);
    float h1f[4] = {0.f, 0.f, 0.f, 0.f}; // h1(t-1), f32
    const int xr = tid / 5, xc = tid - (tid / 5) * 5; // x stagers (tid < 80)

#pragma unroll 1
    for (int t = 0; t < T_; ++t) {
        // prefetch x(t+1) so global latency hides under layer-0 compute
        float xv = 0.f;
        const bool stage = (tid < 80) && (t < T_ - 1);
        if (stage) xv = ldf(x, ((long)(bt0 + xr) * T_ + (t + 1)) * D_ + xc, m32);

        // ---- layer 0: gates = [h0 | x | 1] @ [w_hh0 | w_ih0 | b]^T
        f32x4 a0 = splat4(0.f), a1 = splat4(0.f), a2 = splat4(0.f), a3 = splat4(0.f);
#pragma unroll
        for (int kt = 0; kt < 5; ++kt) {
            a0 = __builtin_amdgcn_mfma_f32_16x16x32_bf16(h0f[kt], wh0c[0][kt], a0, 0, 0, 0);
            a1 = __builtin_amdgcn_mfma_f32_16x16x32_bf16(h0f[kt], wh0c[1][kt], a1, 0, 0, 0);
            a2 = __builtin_amdgcn_mfma_f32_16x16x32_bf16(h0f[kt], wh0c[2][kt], a2, 0, 0, 0);
            a3 = __builtin_amdgcn_mfma_f32_16x16x32_bf16(h0f[kt], wh0c[3][kt], a3, 0, 0, 0);
        }
        ushort h0w[4];
#pragma unroll
        for (int r = 0; r < 4; ++r) {
            float iv = sigf(a0[r]), fv = sigf(a1[r]), gv = tanhf_(a2[r]), ov = sigf(a3[r]);
            float cv = fv * c0[r] + iv * gv;
            cv = fminf(fmaxf(cv, -64.f), 64.f);
            c0[r] = cv;
            h0w[r] = f2b(ov * tanhf_(cv));
        }

        __syncthreads(); // everyone done reading h0s/h1s of step t-1

        // write h0(t), h1(t-1), x(t+1)
#pragma unroll
        for (int r = 0; r < 4; ++r) {
            h0s[(quad * 4 + r) * H0STR + w * 16 + l16] = h0w[r];
            h1s[(quad * 4 + r) * H1STR + w * 16 + l16] = f2b(h1f[r]);
        }
        if (stage) h0s[xr * H0STR + 128 + xc] = f2b(xv);

        __syncthreads(); // writes visible

        // reload h0 frags (serve layer-1 now AND layer-0 of step t+1)
#pragma unroll
        for (int kt = 0; kt < 5; ++kt)
            h0f[kt] = ld16(&h0s[l16 * H0STR + kt * 32 + quad * 8]);

        // ---- layer 1: gates = h0(t) @ w_ih1^T + h1(t-1) @ w_hh1^T + b1
        a0 = splat4(b1v[0]); a1 = splat4(b1v[1]); a2 = splat4(b1v[2]); a3 = splat4(b1v[3]);
#pragma unroll
        for (int kt = 0; kt < 4; ++kt) {
            a0 = __builtin_amdgcn_mfma_f32_16x16x32_bf16(h0f[kt], wi1f[0][kt], a0, 0, 0, 0);
            a1 = __builtin_amdgcn_mfma_f32_16x16x32_bf16(h0f[kt], wi1f[1][kt], a1, 0, 0, 0);
            a2 = __builtin_amdgcn_mfma_f32_16x16x32_bf16(h0f[kt], wi1f[2][kt], a2, 0, 0, 0);
            a3 = __builtin_amdgcn_mfma_f32_16x16x32_bf16(h0f[kt], wi1f[3][kt], a3, 0, 0, 0);
        }
#pragma unroll
        for (int kt = 0; kt < 4; ++kt) {
            bf16x8 hb = ld16(&h1s[l16 * H1STR + kt * 32 + quad * 8]); // h1(t-1) JIT
            a0 = __builtin_amdgcn_mfma_f32_16x16x32_bf16(hb, wh1f[0][kt], a0, 0, 0, 0);
            a1 = __builtin_amdgcn_mfma_f32_16x16x32_bf16(hb, wh1f[1][kt], a1, 0, 0, 0);
            a2 = __builtin_amdgcn_mfma_f32_16x16x32_bf16(hb, wh1f[2][kt], a2, 0, 0, 0);
            a3 = __builtin_amdgcn_mfma_f32_16x16x32_bf16(hb, wh1f[3][kt], a3, 0, 0, 0);
        }
#pragma unroll
        for (int r = 0; r < 4; ++r) {
            float iv = sigf(a0[r]), fv = sigf(a1[r]), gv = tanhf_(a2[r]), ov = sigf(a3[r]);
            float cv = fv * c1[r] + iv * gv;
            cv = fminf(fmaxf(cv, -64.f), 64.f);
            c1[r] = cv;
            h1f[r] = ov * tanhf_(cv);
        }
    }

    // publish final h1(T-1) in f32 (fresh buffer -> no WAR race with loop reads)
#pragma unroll
    for (int r = 0; r < 4; ++r)
        h1fs[(quad * 4 + r) * H_ + w * 16 + l16] = h1f[r];
    __syncthreads();

    // ---- classifier: r = relu(h1 @ cw1^T + cb1); out = r @ cw2^T + cb2
    {
        int m = tid >> 5, j0 = (tid & 31) * 2; // each thread: 2 of 64 hidden outs
        float s0 = ldf(cb1, j0, m32), s1 = ldf(cb1, j0 + 1, m32);
        const float* hr = &h1fs[m * H_];
#pragma unroll 4
        for (int k = 0; k < 128; ++k) {
            float hv = hr[k];
            s0 += hv * ldf(cw1, (long)j0 * 128 + k, m32);
            s1 += hv * ldf(cw1, (long)(j0 + 1) * 128 + k, m32);
        }
        rs[m * 64 + j0]     = fmaxf(s0, 0.f);
        rs[m * 64 + j0 + 1] = fmaxf(s1, 0.f);
    }
    __syncthreads();
    if (tid < 160) {
        int m = tid / 10, cc = tid - m * 10;
        float s = ldf(cb2, cc, m32);
#pragma unroll
        for (int j = 0; j < 64; ++j) s += rs[m * 64 + j] * ldf(cw2, (long)cc * 64 + j, m32);
        long oi = (long)(bt0 + m) * C_ + cc;
        if (m32) ((float*)out)[oi] = s; else ((ushort*)out)[oi] = f2b(s);
    }
    // last_hidden output
    for (int idx = tid; idx < BT * H_; idx += BLK) {
        int m = idx >> 7, k = idx & 127;
        float v = h1fs[m * H_ + k];
        long oi = (long)B_ * C_ + (long)(bt0 + m) * H_ + k;
        if (m32) ((float*)out)[oi] = v; else ((ushort*)out)[oi] = f2b(v);
    }
}

extern "C" void kernel_launch(void* const* d_in, const int* in_sizes, int n_in,
                              void* d_out, int out_size, void* d_ws, size_t ws_size,
                              hipStream_t stream) {
    (void)in_sizes; (void)n_in; (void)out_size; (void)ws_size;
    int* flag = (int*)d_ws;
    hipLaunchKernelGGL(detect_dtype, dim3(1), dim3(256), 0, stream,
                       (const ushort*)d_in[2], flag);
    hipLaunchKernelGGL(lstm2_fused, dim3(B_ / BT), dim3(BLK), 0, stream,
                       d_in[0], d_in[1], d_in[2], d_in[3], d_in[4],
                       d_in[5], d_in[6], d_in[7], d_in[8],
                       d_in[9], d_in[10], d_in[11], d_in[12],
                       (const int*)flag, d_out);
}

// Round 3
// 1892.401 us; speedup vs baseline: 1.1112x; 1.1112x over previous
//
#include <hip/hip_runtime.h>

typedef unsigned short ushort;
typedef unsigned int uint;
typedef __bf16 bf16_t;
typedef bf16_t bf16x8 __attribute__((ext_vector_type(8)));
typedef float f32x4 __attribute__((ext_vector_type(4)));

#define B_ 2048
#define T_ 512
#define D_ 5
#define H_ 128
#define C_ 10
#define BT 16      // batch tile per workgroup
#define BLK 256    // 4 waves -> 1 wave/SIMD -> full 512-reg budget per wave
#define H0STR 168  // h0s row stride in ushorts (160 used + 8 pad)
#define H1STR 136  // h1s row stride (128 used + 8 pad)

static __device__ __forceinline__ float b2f(ushort u) {
    return __builtin_bit_cast(float, ((uint)u) << 16);
}
static __device__ __forceinline__ ushort f2b(float f) {
    uint u = __builtin_bit_cast(uint, f);
    u += 0x7FFFu + ((u >> 16) & 1u);   // RNE
    return (ushort)(u >> 16);
}
// inf-safe without clamps: exp->inf => rcp->0 => sig->0/1, tanh->+-1
static __device__ __forceinline__ float sigf(float x) {
    return __builtin_amdgcn_rcpf(1.0f + __expf(-x));
}
static __device__ __forceinline__ float tanhf_(float x) {
    return 1.0f - 2.0f * __builtin_amdgcn_rcpf(1.0f + __expf(2.0f * x));
}
// dual-dtype scalar load: m32 ? float32 : bf16
static __device__ __forceinline__ float ldf(const void* p, long i, bool m32) {
    return m32 ? ((const float*)p)[i] : b2f(((const ushort*)p)[i]);
}
static __device__ __forceinline__ bf16x8 ld16(const ushort* p) {
    return __builtin_bit_cast(bf16x8, *(const uint4*)p);
}
// dual-dtype 8-element fragment load (init-time only)
static __device__ __forceinline__ bf16x8 ldfrag(const void* p, long idx, bool m32) {
    if (!m32) return ld16((const ushort*)p + idx);
    const float* f = (const float*)p + idx;
    union { ushort u[8]; bf16x8 v; } r;
#pragma unroll
    for (int j = 0; j < 8; ++j) r.u[j] = f2b(f[j]);
    return r.v;
}
static __device__ __forceinline__ f32x4 splat4(float v) {
    f32x4 r = {v, v, v, v};
    return r;
}

// ---- dtype detector (unchanged from round 2; picked f32, passed)
__global__ void detect_dtype(const ushort* __restrict__ w, int* __restrict__ flag) {
    __shared__ int cnt;
    if (threadIdx.x == 0) cnt = 0;
    __syncthreads();
    int local = 0;
    for (int i = threadIdx.x; i < 16384; i += 256)
        if ((uint)(w[i] & 0x7F80u) >= 0x4180u) ++local;   // |v| >= 16
    atomicAdd(&cnt, local);
    __syncthreads();
    if (threadIdx.x == 0) *flag = (cnt > 512) ? 1 : 0;
}

__global__ __launch_bounds__(BLK, 1) void lstm2_fused(
    const void* __restrict__ x,
    const void* __restrict__ wih0, const void* __restrict__ whh0,
    const void* __restrict__ bih0, const void* __restrict__ bhh0,
    const void* __restrict__ wih1, const void* __restrict__ whh1,
    const void* __restrict__ bih1, const void* __restrict__ bhh1,
    const void* __restrict__ cw1, const void* __restrict__ cb1,
    const void* __restrict__ cw2, const void* __restrict__ cb2,
    const int* __restrict__ flag, void* __restrict__ out)
{
    // double-buffered recurrent state: 1 barrier/step
    __shared__ __align__(16) ushort h0s[2][BT * H0STR]; // [.][row][0..127]=h0, [128..132]=x_t, [133]=1.0, rest 0
    __shared__ __align__(16) ushort h1s[2][BT * H1STR];
    __shared__ float h1fs[BT * H_];                     // final h1 in f32
    __shared__ float rs[BT * 64];                       // classifier hidden

    const bool m32 = (*flag) != 0;   // uniform
    const int tid  = threadIdx.x;
    const int w    = tid >> 6;       // wave 0..3
    const int lane = tid & 63;
    const int quad = lane >> 4;
    const int l16  = lane & 15;
    const int bt0  = blockIdx.x * BT;

    // ---- stage x(0)+const cols into buf0; const cols into buf1 (written once)
    for (int i = tid; i < BT * 32; i += BLK) {
        int row = i >> 5, cc = i & 31;
        ushort c  = (cc == 5) ? (ushort)0x3F80 : (ushort)0;   // bf16(1.0) bias col
        ushort v0 = (cc < 5) ? f2b(ldf(x, ((long)(bt0 + row) * T_) * D_ + cc, m32)) : c;
        h0s[0][row * H0STR + 128 + cc] = v0;
        h0s[1][row * H0STR + 128 + cc] = c;
    }
    // zero h1s[1] (h1(-1) = 0, read at iter 0)
    for (int i = tid; i < BT * H_; i += BLK) {
        int row = i >> 7, cc = i & 127;
        h1s[1][row * H1STR + cc] = 0;
    }

    // ---- register-resident weight fragments. Each wave: 4 gates x 2 n-subtiles.
    // B-frag (16x16x32): lane holds W[n][k = kt*32 + quad*8 + j], j=0..7
    bf16x8 wh0c[4][2][5]; // layer0: kt 0..3 = w_hh0, kt 4 = [w_ih0 | bias | 0]
    bf16x8 wi1f[4][2][4]; // layer1, h0 part
    bf16x8 wh1f[4][2][4]; // layer1, h1 part
    float  b1v[4][2];
#pragma unroll
    for (int g = 0; g < 4; ++g) {
#pragma unroll
        for (int s = 0; s < 2; ++s) {
            const int n = g * 128 + w * 32 + s * 16 + l16; // row in 4H=512 gate dim
#pragma unroll
            for (int kt = 0; kt < 4; ++kt) {
                wh0c[g][s][kt] = ldfrag(whh0, (long)n * 128 + kt * 32 + quad * 8, m32);
                wi1f[g][s][kt] = ldfrag(wih1, (long)n * 128 + kt * 32 + quad * 8, m32);
                wh1f[g][s][kt] = ldfrag(whh1, (long)n * 128 + kt * 32 + quad * 8, m32);
            }
            union { ushort u[8]; bf16x8 v; } xt;
#pragma unroll
            for (int j = 0; j < 8; ++j) xt.u[j] = 0;
            if (quad == 0) { // only k=128..135 live in the x-tile
#pragma unroll
                for (int j = 0; j < 5; ++j) xt.u[j] = f2b(ldf(wih0, (long)n * D_ + j, m32));
                xt.u[5] = f2b(ldf(bih0, n, m32) + ldf(bhh0, n, m32)); // bias via 1.0 col
            }
            wh0c[g][s][4] = xt.v;
            b1v[g][s] = ldf(bih1, n, m32) + ldf(bhh1, n, m32);
        }
    }

    __syncthreads();

    // ---- recurrent state
    bf16x8 h0f[5];
    {
        uint4 z = make_uint4(0, 0, 0, 0);
        h0f[0] = h0f[1] = h0f[2] = h0f[3] = __builtin_bit_cast(bf16x8, z); // h0(-1)=0
    }
    h0f[4] = ld16(&h0s[0][l16 * H0STR + 128 + quad * 8]); // x(0) + bias col

    f32x4 c0[2] = {splat4(0.f), splat4(0.f)};
    f32x4 c1[2] = {splat4(0.f), splat4(0.f)};
    float h1o[2][4] = {{0.f, 0.f, 0.f, 0.f}, {0.f, 0.f, 0.f, 0.f}};
    const int xr = tid / 5, xc = tid - (tid / 5) * 5; // x stagers (tid < 80)

#pragma unroll 1
    for (int t = 0; t < T_; ++t) {
        const int wb = (t + 1) & 1; // buffer produced this iter, read post-barrier
        // prefetch x(t+1): global latency hides under layer-0 compute
        float xv = 0.f;
        const bool stage = (tid < 80) && (t < T_ - 1);
        if (stage) xv = ldf(x, ((long)(bt0 + xr) * T_ + (t + 1)) * D_ + xc, m32);

        // ---- layer 0: gates = [h0 | x | 1] @ [w_hh0 | w_ih0 | b]^T
        f32x4 a[4][2];
#pragma unroll
        for (int g = 0; g < 4; ++g)
#pragma unroll
            for (int s = 0; s < 2; ++s) a[g][s] = splat4(0.f);
#pragma unroll
        for (int kt = 0; kt < 5; ++kt)
#pragma unroll
            for (int g = 0; g < 4; ++g)
#pragma unroll
                for (int s = 0; s < 2; ++s)
                    a[g][s] = __builtin_amdgcn_mfma_f32_16x16x32_bf16(
                        h0f[kt], wh0c[g][s][kt], a[g][s], 0, 0, 0);
        ushort h0w[2][4];
#pragma unroll
        for (int s = 0; s < 2; ++s)
#pragma unroll
            for (int r = 0; r < 4; ++r) {
                float iv = sigf(a[0][s][r]), fv = sigf(a[1][s][r]);
                float gv = tanhf_(a[2][s][r]), ov = sigf(a[3][s][r]);
                float cv = fv * c0[s][r] + iv * gv;
                c0[s][r] = cv;
                h0w[s][r] = f2b(ov * tanhf_(cv));
            }

        // write h0(t) + x(t+1) into buffer wb (h1(t-1) already there from last iter)
#pragma unroll
        for (int s = 0; s < 2; ++s)
#pragma unroll
            for (int r = 0; r < 4; ++r)
                h0s[wb][(quad * 4 + r) * H0STR + w * 32 + s * 16 + l16] = h0w[s][r];
        if (stage) h0s[wb][xr * H0STR + 128 + xc] = f2b(xv);

        __syncthreads(); // single barrier per step (double-buffered WAR-safe)

        // reload h0 frags (serve layer-1 now AND layer-0 of step t+1)
#pragma unroll
        for (int kt = 0; kt < 5; ++kt)
            h0f[kt] = ld16(&h0s[wb][l16 * H0STR + kt * 32 + quad * 8]);
        bf16x8 hb[4];
#pragma unroll
        for (int kt = 0; kt < 4; ++kt)
            hb[kt] = ld16(&h1s[wb][l16 * H1STR + kt * 32 + quad * 8]);

        // ---- layer 1: gates = h0(t) @ w_ih1^T + h1(t-1) @ w_hh1^T + b1
#pragma unroll
        for (int g = 0; g < 4; ++g)
#pragma unroll
            for (int s = 0; s < 2; ++s) a[g][s] = splat4(b1v[g][s]);
#pragma unroll
        for (int kt = 0; kt < 4; ++kt)
#pragma unroll
            for (int g = 0; g < 4; ++g)
#pragma unroll
                for (int s = 0; s < 2; ++s)
                    a[g][s] = __builtin_amdgcn_mfma_f32_16x16x32_bf16(
                        h0f[kt], wi1f[g][s][kt], a[g][s], 0, 0, 0);
#pragma unroll
        for (int kt = 0; kt < 4; ++kt)
#pragma unroll
            for (int g = 0; g < 4; ++g)
#pragma unroll
                for (int s = 0; s < 2; ++s)
                    a[g][s] = __builtin_amdgcn_mfma_f32_16x16x32_bf16(
                        hb[kt], wh1f[g][s][kt], a[g][s], 0, 0, 0);
#pragma unroll
        for (int s = 0; s < 2; ++s)
#pragma unroll
            for (int r = 0; r < 4; ++r) {
                float iv = sigf(a[0][s][r]), fv = sigf(a[1][s][r]);
                float gv = tanhf_(a[2][s][r]), ov = sigf(a[3][s][r]);
                float cv = fv * c1[s][r] + iv * gv;
                c1[s][r] = cv;
                float hv = ov * tanhf_(cv);
                h1o[s][r] = hv;
                // h1(t) -> buffer read at iter t+1 (= wb^1); WAR-safe across barrier(t)
                h1s[wb ^ 1][(quad * 4 + r) * H1STR + w * 32 + s * 16 + l16] = f2b(hv);
            }
    }

    // publish final h1(T-1) in f32
#pragma unroll
    for (int s = 0; s < 2; ++s)
#pragma unroll
        for (int r = 0; r < 4; ++r)
            h1fs[(quad * 4 + r) * H_ + w * 32 + s * 16 + l16] = h1o[s][r];
    __syncthreads();

    // ---- classifier: r = relu(h1 @ cw1^T + cb1); out = r @ cw2^T + cb2
    {
        int m = tid >> 4, j0 = (tid & 15) * 4; // 16 rows x 16 threads, 4 outs each
        float s0 = ldf(cb1, j0, m32), s1 = ldf(cb1, j0 + 1, m32);
        float s2 = ldf(cb1, j0 + 2, m32), s3 = ldf(cb1, j0 + 3, m32);
        const float* hr = &h1fs[m * H_];
#pragma unroll 4
        for (int k = 0; k < 128; ++k) {
            float hv = hr[k];
            s0 += hv * ldf(cw1, (long)j0 * 128 + k, m32);
            s1 += hv * ldf(cw1, (long)(j0 + 1) * 128 + k, m32);
            s2 += hv * ldf(cw1, (long)(j0 + 2) * 128 + k, m32);
            s3 += hv * ldf(cw1, (long)(j0 + 3) * 128 + k, m32);
        }
        rs[m * 64 + j0]     = fmaxf(s0, 0.f);
        rs[m * 64 + j0 + 1] = fmaxf(s1, 0.f);
        rs[m * 64 + j0 + 2] = fmaxf(s2, 0.f);
        rs[m * 64 + j0 + 3] = fmaxf(s3, 0.f);
    }
    __syncthreads();
    if (tid < 160) {
        int m = tid / 10, cc = tid - m * 10;
        float s = ldf(cb2, cc, m32);
#pragma unroll
        for (int j = 0; j < 64; ++j) s += rs[m * 64 + j] * ldf(cw2, (long)cc * 64 + j, m32);
        long oi = (long)(bt0 + m) * C_ + cc;
        if (m32) ((float*)out)[oi] = s; else ((ushort*)out)[oi] = f2b(s);
    }
    // last_hidden output
    for (int idx = tid; idx < BT * H_; idx += BLK) {
        int m = idx >> 7, k = idx & 127;
        float v = h1fs[m * H_ + k];
        long oi = (long)B_ * C_ + (long)(bt0 + m) * H_ + k;
        if (m32) ((float*)out)[oi] = v; else ((ushort*)out)[oi] = f2b(v);
    }
}

extern "C" void kernel_launch(void* const* d_in, const int* in_sizes, int n_in,
                              void* d_out, int out_size, void* d_ws, size_t ws_size,
                              hipStream_t stream) {
    (void)in_sizes; (void)n_in; (void)out_size; (void)ws_size;
    int* flag = (int*)d_ws;
    hipLaunchKernelGGL(detect_dtype, dim3(1), dim3(256), 0, stream,
                       (const ushort*)d_in[2], flag);
    hipLaunchKernelGGL(lstm2_fused, dim3(B_ / BT), dim3(BLK), 0, stream,
                       d_in[0], d_in[1], d_in[2], d_in[3], d_in[4],
                       d_in[5], d_in[6], d_in[7], d_in[8],
                       d_in[9], d_in[10], d_in[11], d_in[12],
                       (const int*)flag, d_out);
}